// Round 8
// baseline (318.333 us; speedup 1.0000x reference)
//
#include <hip/hip_runtime.h>
#include <hip/hip_cooperative_groups.h>
#include <math.h>

namespace cg = cooperative_groups;

#define B_   128
#define T_   50
#define MI_  32
#define E_   128
#define EW_  16
#define D_   144
#define G_   432        // 3*D
#define N_   (B_*T_)    // 6400

// ---------------------------------------------------------------------------
// Mega-kernel: embed -> grid.sync -> gi GEMM -> grid.sync -> GRU -> grid.sync
// -> fc GEMM.  One dispatch: its dur_us IS the total GPU time (instrument for
// the ~132us invisible block), and all launch/drain gaps disappear.
// Grid 256 x 512.  One 52KB LDS arena aliased by phase.
// ---------------------------------------------------------------------------

template<int CTRL>
__device__ __forceinline__ float dpp_xor_add(float x) {
    int y = __builtin_amdgcn_mov_dpp(__float_as_int(x), CTRL, 0xF, 0xF, true);
    return x + __int_as_float(y);
}

// 64x64 GEMM tile on a 256-thread sub-unit (stid 0..255).  C = A@Bw^T + bias,
// K=144.  Both sub-units of a block run lockstep (same barrier cadence);
// invalid subs execute loops with zeroed/guarded memory ops.
__device__ __forceinline__ void gemm_tile_256(
    int stid, bool valid, int row0, int col0,
    const float* __restrict__ A, const float* __restrict__ Bw,
    const float* __restrict__ bias, float* __restrict__ C,
    int N, float* As, float* Bs)
{
    int tx = stid & 15;
    int ty = stid >> 4;
    float acc[4][4] = {};
    int sr = stid >> 2;
    int skq0 = stid & 3;

    for (int k0 = 0; k0 < 144; k0 += 48) {
        __syncthreads();
        #pragma unroll
        for (int i = 0; i < 3; ++i) {
            int kq = skq0 + i * 4;          // 0..11
            float4 a = make_float4(0.f, 0.f, 0.f, 0.f);
            float4 b = make_float4(0.f, 0.f, 0.f, 0.f);
            if (valid)
                a = *(const float4*)&A[(size_t)(row0 + sr) * 144 + k0 + kq * 4];
            int nrow = col0 + sr;
            if (valid && nrow < N)
                b = *(const float4*)&Bw[(size_t)nrow * 144 + k0 + kq * 4];
            As[(kq * 4 + 0) * 68 + sr] = a.x;
            As[(kq * 4 + 1) * 68 + sr] = a.y;
            As[(kq * 4 + 2) * 68 + sr] = a.z;
            As[(kq * 4 + 3) * 68 + sr] = a.w;
            Bs[(kq * 4 + 0) * 68 + sr] = b.x;
            Bs[(kq * 4 + 1) * 68 + sr] = b.y;
            Bs[(kq * 4 + 2) * 68 + sr] = b.z;
            Bs[(kq * 4 + 3) * 68 + sr] = b.w;
        }
        __syncthreads();

        #pragma unroll 4
        for (int k = 0; k < 48; ++k) {
            float4 a4 = *(const float4*)&As[k * 68 + ty * 4];
            float4 b4 = *(const float4*)&Bs[k * 68 + tx * 4];
            float av[4] = {a4.x, a4.y, a4.z, a4.w};
            float bv[4] = {b4.x, b4.y, b4.z, b4.w};
            #pragma unroll
            for (int i = 0; i < 4; ++i)
                #pragma unroll
                for (int j = 0; j < 4; ++j)
                    acc[i][j] = fmaf(av[i], bv[j], acc[i][j]);
        }
    }

    int c = col0 + tx * 4;
    if (valid && c < N) {
        float4 bb = *(const float4*)&bias[c];
        #pragma unroll
        for (int i = 0; i < 4; ++i) {
            int r = row0 + ty * 4 + i;
            float4 o;
            o.x = acc[i][0] + bb.x;
            o.y = acc[i][1] + bb.y;
            o.z = acc[i][2] + bb.z;
            o.w = acc[i][3] + bb.w;
            *(float4*)&C[(size_t)r * N + c] = o;
        }
    }
}

__global__ __launch_bounds__(512, 2) void mega_kernel(
    const int*   __restrict__ x,          // [N_][33]
    const float* __restrict__ hidden,     // [1][128][144]
    const float* __restrict__ encode_w,   // [100000][128] (row 0 == 0)
    const float* __restrict__ wchange_w,  // [2][16]
    const float* __restrict__ w_ih,       // [432][144]
    const float* __restrict__ w_hh,       // [432][144]
    const float* __restrict__ b_ih,       // [432]
    const float* __restrict__ b_hh,       // [432]
    const float* __restrict__ fc_w,       // [128][144]
    const float* __restrict__ fc_b,       // [128]
    float* __restrict__ out,              // [N_][128] ++ [128][144]
    float* __restrict__ seq,              // ws [N_][144]
    float* __restrict__ gi,               // ws [N_][432]
    float* __restrict__ hseq)             // ws [N_][144]
{
    cg::grid_group grid = cg::this_grid();

    __shared__ __align__(16) float smem[13056];   // 52.2 KB arena

    int bid = blockIdx.x;        // 0..255
    int tid = threadIdx.x;       // 0..511
    int sub = tid >> 8;          // 0/1: 256-thread sub-unit
    int stid = tid & 255;

    // ===================== Phase 1: basket embedding =====================
    // Two samples per block per round, 13 rounds (6656 slots >= 6400).
    {
        float* eb   = smem + sub * 4352;
        int*   xi   = (int*)eb;               // 33 ints
        float* part = eb + 48;                // 32 x 132
        float* cntf = eb + 48 + 4224;         // 32
        int i = stid >> 3;                    // item
        int j = stid & 7;                     // 16-col chunk

        for (int r = 0; r < 13; ++r) {
            int n = r * 512 + 2 * bid + sub;
            bool v = (n < N_);
            if (v && stid < 33) xi[stid] = x[n * 33 + stid];
            __syncthreads();

            if (v) {
                int it = xi[i];
                const float* row = &encode_w[(size_t)it * E_];
                float4 v0 = *(const float4*)&row[16 * j + 0];
                float4 v1 = *(const float4*)&row[16 * j + 4];
                float4 v2 = *(const float4*)&row[16 * j + 8];
                float4 v3 = *(const float4*)&row[16 * j + 12];
                float* p = &part[i * 132 + 16 * j];
                *(float4*)&p[0]  = v0;
                *(float4*)&p[4]  = v1;
                *(float4*)&p[8]  = v2;
                *(float4*)&p[12] = v3;
                if (j == 0) cntf[i] = (it != 0) ? 1.f : 0.f;
            }
            __syncthreads();

            if (v && stid < E_) {
                float s = 0.f, cn = 0.f;
                #pragma unroll
                for (int k = 0; k < 32; ++k) {
                    s  += part[k * 132 + stid];
                    cn += cntf[k];
                }
                seq[n * D_ + stid] = s / fmaxf(cn, 1.f);
            } else if (v && stid < E_ + EW_) {
                int c = stid - E_;
                seq[n * D_ + E_ + c] = wchange_w[xi[32] * EW_ + c];
            }
            __syncthreads();   // protect xi/part reuse next round
        }
    }
    grid.sync();

    // ===================== Phase 2: gi = seq @ w_ih^T + b_ih =====================
    // 700 tiles (100 x 7), 2 tiles/block/round, 2 rounds.
    {
        float* gb = smem + sub * 6528;
        float* As = gb;
        float* Bs = gb + 3264;
        for (int r = 0; r < 2; ++r) {
            int t = r * 512 + 2 * bid + sub;
            bool valid = (t < 700);
            int tt = valid ? t : 0;
            int row0 = (tt / 7) * 64;
            int col0 = (tt % 7) * 64;
            gemm_tile_256(stid, valid, row0, col0, seq, w_ih, b_ih, gi, G_, As, Bs);
        }
    }
    grid.sync();

    // ===================== Phase 3: GRU (v4 512-thread mapping) =====================
    if (bid < B_) {
        int b = bid;
        int g = tid >> 3;       // 0..63 -> rows 7g..7g+6
        int s = tid & 7;        // k-chunk [20s,20s+20)
        int k0 = s * 20;

        float* h    = smem;          // 160 (k-padded)
        float* gh   = smem + 160;    // 432
        float* hbuf = smem + 592;    // 7200

        float w[7][20];
        #pragma unroll
        for (int rr = 0; rr < 7; ++rr) {
            int row = 7 * g + rr;
            if (row > 431) row = 431;
            const float* wrow = &w_hh[(size_t)row * D_];
            #pragma unroll
            for (int q = 0; q < 5; ++q) {
                int k = k0 + 4 * q;
                float4 t4 = make_float4(0.f, 0.f, 0.f, 0.f);
                if (k < D_) t4 = *(const float4*)&wrow[k];
                w[rr][4 * q + 0] = t4.x;
                w[rr][4 * q + 1] = t4.y;
                w[rr][4 * q + 2] = t4.z;
                w[rr][4 * q + 3] = t4.w;
            }
        }
        int myrow = 7 * g + s;
        float bias = b_hh[(myrow > 431) ? 431 : myrow];

        if (tid < 160) h[tid] = (tid < D_) ? hidden[b * D_ + tid] : 0.f;
        __syncthreads();

        for (int t = 0; t < T_; ++t) {
            int n = b * T_ + t;
            float gir = 0.f, giz = 0.f, gin = 0.f;
            if (tid < D_) {
                gir = gi[(size_t)n * G_ + tid];
                giz = gi[(size_t)n * G_ + D_ + tid];
                gin = gi[(size_t)n * G_ + 2 * D_ + tid];
            }

            float hv[20];
            #pragma unroll
            for (int q = 0; q < 5; ++q) {
                float4 t4 = *(const float4*)&h[k0 + 4 * q];
                hv[4 * q + 0] = t4.x;
                hv[4 * q + 1] = t4.y;
                hv[4 * q + 2] = t4.z;
                hv[4 * q + 3] = t4.w;
            }

            float a0 = 0.f, a1 = 0.f, a2 = 0.f, a3 = 0.f, a4 = 0.f, a5 = 0.f, a6 = 0.f;
            #pragma unroll
            for (int kk = 0; kk < 20; ++kk) {
                float hk = hv[kk];
                a0 = fmaf(w[0][kk], hk, a0);
                a1 = fmaf(w[1][kk], hk, a1);
                a2 = fmaf(w[2][kk], hk, a2);
                a3 = fmaf(w[3][kk], hk, a3);
                a4 = fmaf(w[4][kk], hk, a4);
                a5 = fmaf(w[5][kk], hk, a5);
                a6 = fmaf(w[6][kk], hk, a6);
            }

            a0 = dpp_xor_add<0xB1>(a0); a0 = dpp_xor_add<0x4E>(a0); a0 = dpp_xor_add<0x141>(a0);
            a1 = dpp_xor_add<0xB1>(a1); a1 = dpp_xor_add<0x4E>(a1); a1 = dpp_xor_add<0x141>(a1);
            a2 = dpp_xor_add<0xB1>(a2); a2 = dpp_xor_add<0x4E>(a2); a2 = dpp_xor_add<0x141>(a2);
            a3 = dpp_xor_add<0xB1>(a3); a3 = dpp_xor_add<0x4E>(a3); a3 = dpp_xor_add<0x141>(a3);
            a4 = dpp_xor_add<0xB1>(a4); a4 = dpp_xor_add<0x4E>(a4); a4 = dpp_xor_add<0x141>(a4);
            a5 = dpp_xor_add<0xB1>(a5); a5 = dpp_xor_add<0x4E>(a5); a5 = dpp_xor_add<0x141>(a5);
            a6 = dpp_xor_add<0xB1>(a6); a6 = dpp_xor_add<0x4E>(a6); a6 = dpp_xor_add<0x141>(a6);

            float myacc = a0;
            if (s == 1) myacc = a1;
            if (s == 2) myacc = a2;
            if (s == 3) myacc = a3;
            if (s == 4) myacc = a4;
            if (s == 5) myacc = a5;
            if (s == 6) myacc = a6;
            if (s < 7 && myrow < G_) gh[myrow] = myacc + bias;
            __syncthreads();

            if (tid < D_) {
                float r = 1.f / (1.f + __expf(-(gir + gh[tid])));
                float z = 1.f / (1.f + __expf(-(giz + gh[D_ + tid])));
                float narg = gin + r * gh[2 * D_ + tid];
                narg = fminf(fmaxf(narg, -15.f), 15.f);
                float e2 = __expf(-2.f * narg);
                float nn = (1.f - e2) / (1.f + e2);
                float hn = (1.f - z) * nn + z * h[tid];
                hbuf[t * D_ + tid] = hn;
                h[tid] = hn;
            }
            __syncthreads();
        }

        // flush hbuf -> hseq, h -> hlast (= out tail)
        {
            const float4* src = (const float4*)hbuf;
            float4* dst = (float4*)&hseq[(size_t)b * T_ * D_];
            for (int i2 = tid; i2 < (T_ * D_) / 4; i2 += 512) dst[i2] = src[i2];
        }
        if (tid < D_) out[(size_t)N_ * E_ + b * D_ + tid] = h[tid];
    }
    grid.sync();

    // ===================== Phase 4: out = hseq @ fc_w^T + fc_b =====================
    // 200 tiles (100 x 2), 2 tiles/block, 1 round.
    {
        float* gb = smem + sub * 6528;
        float* As = gb;
        float* Bs = gb + 3264;
        int t = 2 * bid + sub;
        bool valid = (t < 200);
        int tt = valid ? t : 0;
        int row0 = (tt >> 1) * 64;
        int col0 = (tt & 1) * 64;
        gemm_tile_256(stid, valid, row0, col0, hseq, fc_w, fc_b, out, E_, As, Bs);
    }
}

// ---------------------------------------------------------------------------
extern "C" void kernel_launch(void* const* d_in, const int* in_sizes, int n_in,
                              void* d_out, int out_size, void* d_ws, size_t ws_size,
                              hipStream_t stream)
{
    const int*   x         = (const int*)d_in[0];
    // d_in[1] = lengths (unused by the reference computation)
    const float* hidden    = (const float*)d_in[2];
    const float* encode_w  = (const float*)d_in[3];
    const float* wchange_w = (const float*)d_in[4];
    const float* w_ih      = (const float*)d_in[5];
    const float* w_hh      = (const float*)d_in[6];
    const float* b_ih      = (const float*)d_in[7];
    const float* b_hh      = (const float*)d_in[8];
    const float* fc_w      = (const float*)d_in[9];
    const float* fc_b      = (const float*)d_in[10];

    float* out  = (float*)d_out;             // [N_][128] then [128][144]
    float* ws   = (float*)d_ws;
    float* seq  = ws;                        //   921600 floats
    float* gi   = ws + 921600;               //  2764800 floats
    float* hseq = ws + 921600 + 2764800;     //   921600 floats

    void* args[] = {
        (void*)&x, (void*)&hidden, (void*)&encode_w, (void*)&wchange_w,
        (void*)&w_ih, (void*)&w_hh, (void*)&b_ih, (void*)&b_hh,
        (void*)&fc_w, (void*)&fc_b,
        (void*)&out, (void*)&seq, (void*)&gi, (void*)&hseq
    };
    hipLaunchCooperativeKernel((void*)mega_kernel, dim3(256), dim3(512),
                               args, 0, stream);
}

// Round 9
// 190.852 us; speedup vs baseline: 1.6680x; 1.6680x over previous
//
#include <hip/hip_runtime.h>
#include <math.h>

#define B_   128
#define T_   50
#define MI_  32
#define E_   128
#define EW_  16
#define D_   144
#define G_   432        // 3*D
#define N_   (B_*T_)    // 6400

// ---------------------------------------------------------------------------
// K1: basket embedding v2 — parallel gather (R7, kept).
// ---------------------------------------------------------------------------
__global__ __launch_bounds__(256) void embed_kernel(
    const int* __restrict__ x,            // [N_][33]
    const float* __restrict__ encode_w,   // [100000][128]  (row 0 == 0)
    const float* __restrict__ wchange_w,  // [2][16]
    float* __restrict__ seq)              // [N_][144]
{
    int n = blockIdx.x;
    int tid = threadIdx.x;
    int i = tid >> 3;        // item 0..31
    int j = tid & 7;         // col chunk [16j, 16j+16)

    __shared__ int xi[33];
    __shared__ __align__(16) float part[32 * 132];
    __shared__ float cntf[32];

    if (tid < 33) xi[tid] = x[n * 33 + tid];
    __syncthreads();

    int it = xi[i];
    const float* row = &encode_w[(size_t)it * E_];
    float4 v0 = *(const float4*)&row[16 * j + 0];
    float4 v1 = *(const float4*)&row[16 * j + 4];
    float4 v2 = *(const float4*)&row[16 * j + 8];
    float4 v3 = *(const float4*)&row[16 * j + 12];

    float* p = &part[i * 132 + 16 * j];
    *(float4*)&p[0]  = v0;
    *(float4*)&p[4]  = v1;
    *(float4*)&p[8]  = v2;
    *(float4*)&p[12] = v3;
    if (j == 0) cntf[i] = (it != 0) ? 1.f : 0.f;
    __syncthreads();

    if (tid < E_) {
        int c = tid;
        float s = 0.f, cn = 0.f;
        #pragma unroll
        for (int k = 0; k < 32; ++k) {
            s  += part[k * 132 + c];
            cn += cntf[k];
        }
        seq[n * D_ + c] = s / fmaxf(cn, 1.f);
    } else if (tid < E_ + EW_) {
        int c = tid - E_;
        seq[n * D_ + E_ + c] = wchange_w[xi[32] * EW_ + c];
    }
}

// ---------------------------------------------------------------------------
// K2/K4: C[M][N] = A[M][144] * Bw[N][144]^T + bias[N].  K fixed = 144.
// 64x64 tile, k-major LDS (pad 68 words -> conflict-free b128 reads), BK=48.
// ---------------------------------------------------------------------------
#define GK   144
#define GBK  48
#define GPAD 68

__global__ __launch_bounds__(256) void gemm_bias_kernel(
    const float* __restrict__ A,
    const float* __restrict__ Bw,
    const float* __restrict__ bias,
    float* __restrict__ C,
    int M, int N)
{
    __shared__ float As[GBK * GPAD];
    __shared__ float Bs[GBK * GPAD];

    int tid = threadIdx.x;
    int row0 = blockIdx.x * 64;
    int col0 = blockIdx.y * 64;
    int tx = tid & 15;
    int ty = tid >> 4;

    float acc[4][4] = {};

    int sr = tid >> 2;
    int skq0 = tid & 3;

    for (int k0 = 0; k0 < GK; k0 += GBK) {
        __syncthreads();
        #pragma unroll
        for (int i = 0; i < 3; ++i) {
            int kq = skq0 + i * 4;
            float4 a = *(const float4*)&A[(size_t)(row0 + sr) * GK + k0 + kq * 4];
            int nrow = col0 + sr;
            float4 b = make_float4(0.f, 0.f, 0.f, 0.f);
            if (nrow < N)
                b = *(const float4*)&Bw[(size_t)nrow * GK + k0 + kq * 4];
            As[(kq * 4 + 0) * GPAD + sr] = a.x;
            As[(kq * 4 + 1) * GPAD + sr] = a.y;
            As[(kq * 4 + 2) * GPAD + sr] = a.z;
            As[(kq * 4 + 3) * GPAD + sr] = a.w;
            Bs[(kq * 4 + 0) * GPAD + sr] = b.x;
            Bs[(kq * 4 + 1) * GPAD + sr] = b.y;
            Bs[(kq * 4 + 2) * GPAD + sr] = b.z;
            Bs[(kq * 4 + 3) * GPAD + sr] = b.w;
        }
        __syncthreads();

        #pragma unroll 4
        for (int k = 0; k < GBK; ++k) {
            float4 a4 = *(const float4*)&As[k * GPAD + ty * 4];
            float4 b4 = *(const float4*)&Bs[k * GPAD + tx * 4];
            float av[4] = {a4.x, a4.y, a4.z, a4.w};
            float bv[4] = {b4.x, b4.y, b4.z, b4.w};
            #pragma unroll
            for (int i = 0; i < 4; ++i)
                #pragma unroll
                for (int j = 0; j < 4; ++j)
                    acc[i][j] = fmaf(av[i], bv[j], acc[i][j]);
        }
    }

    int c = col0 + tx * 4;
    if (c < N) {
        float4 bb = *(const float4*)&bias[c];
        #pragma unroll
        for (int i = 0; i < 4; ++i) {
            int r = row0 + ty * 4 + i;
            float4 o;
            o.x = acc[i][0] + bb.x;
            o.y = acc[i][1] + bb.y;
            o.z = acc[i][2] + bb.z;
            o.w = acc[i][3] + bb.w;
            *(float4*)&C[(size_t)r * N + c] = o;
        }
    }
}

// ---------------------------------------------------------------------------
// K3: GRU v7.  768 threads = 12 waves, 3/SIMD BALANCED (evidence: v4's 8
// waves < v3's 9 waves despite lower issue -> latency-hiding-limited; raise
// TLP).  S=16 k-split, chunk 10 (K padded 160): thread (g=tid>>4, s=tid&15)
// owns rows 9g..9g+8 (48*9=432 exact) x k in [10s,10s+10).  w = 9x10 = 90
// VGPRs.  Per-wave VALU: 90 fmac + 72 DPP (4-stage butterfly over 16 lanes:
// quad_perm xor1/xor2, row_half_mirror, row_mirror) ~= 374cy vs v3's 424,
// busiest-SIMD 1122 vs 1272, LDS instrs 36 vs 45 (2 b128 + 1 b64 per lane,
// max 2-way bank aliasing = free).  Gate phase + 2-barrier cadence = v3.
// ---------------------------------------------------------------------------
template<int CTRL>
__device__ __forceinline__ float dpp_xor_add(float x) {
    int y = __builtin_amdgcn_mov_dpp(__float_as_int(x), CTRL, 0xF, 0xF, true);
    return x + __int_as_float(y);
}

// 16-lane all-reduce: after xor1,xor2 each quad is uniform, so
// row_half_mirror (l^7) lands in quad l^4, row_mirror (l^15) in 8-group l^8.
__device__ __forceinline__ float reduce16(float x) {
    x = dpp_xor_add<0xB1>(x);    // quad_perm [1,0,3,2]  : += l^1
    x = dpp_xor_add<0x4E>(x);    // quad_perm [2,3,0,1]  : += l^2
    x = dpp_xor_add<0x141>(x);   // row_half_mirror      : += l^4 (quads uniform)
    x = dpp_xor_add<0x140>(x);   // row_mirror           : += l^8 (8-grps uniform)
    return x;
}

__global__ __launch_bounds__(768) void gru_kernel(
    const float* __restrict__ gi,     // [N_][432]
    const float* __restrict__ w_hh,   // [432][144]
    const float* __restrict__ b_hh,   // [432]
    const float* __restrict__ h0,     // [128][144]
    float* __restrict__ hseq,         // [N_][144]
    float* __restrict__ hlast)        // [128][144]
{
    int b = blockIdx.x;
    int tid = threadIdx.x;
    int g = tid >> 4;       // 0..47  -> rows 9g..9g+8
    int s = tid & 15;       // k-chunk [10s, 10s+10)
    int k0 = s * 10;

    __shared__ __align__(16) float h[160];   // k-padded; [144..159] stay 0
    __shared__ float gh[G_];

    // one-time: weights into VGPRs (zero past k=143)
    float w[9][10];
    #pragma unroll
    for (int r = 0; r < 9; ++r) {
        const float* wrow = &w_hh[(size_t)(9 * g + r) * D_];
        // piece 1: float4 at k0
        float4 t4a = make_float4(0.f, 0.f, 0.f, 0.f);
        if (k0 + 3 < D_) t4a = *(const float4*)&wrow[k0];
        // piece 2: float4 at k0+4
        float4 t4b = make_float4(0.f, 0.f, 0.f, 0.f);
        if (k0 + 7 < D_) t4b = *(const float4*)&wrow[k0 + 4];
        // piece 3: float2 at k0+8
        float2 t2 = make_float2(0.f, 0.f);
        if (k0 + 9 < D_) t2 = *(const float2*)&wrow[k0 + 8];
        w[r][0] = t4a.x; w[r][1] = t4a.y; w[r][2] = t4a.z; w[r][3] = t4a.w;
        w[r][4] = t4b.x; w[r][5] = t4b.y; w[r][6] = t4b.z; w[r][7] = t4b.w;
        w[r][8] = t2.x;  w[r][9] = t2.y;
    }
    float bias = (s < 9) ? b_hh[9 * g + s] : 0.f;

    if (tid < 160) h[tid] = (tid < D_) ? h0[b * D_ + tid] : 0.f;
    __syncthreads();

    for (int t = 0; t < T_; ++t) {
        int n = b * T_ + t;
        // prefetch gi (L2-resident; overlaps the LDS reads + dot phase)
        float gir = 0.f, giz = 0.f, gin = 0.f;
        if (tid < D_) {
            gir = gi[(size_t)n * G_ + tid];
            giz = gi[(size_t)n * G_ + D_ + tid];
            gin = gi[(size_t)n * G_ + 2 * D_ + tid];
        }

        // h chunk: 2 b128 + 1 b64, banks max 2-way aliased (free)
        float hv[10];
        {
            float4 a4 = *(const float4*)&h[k0];
            float4 b4 = *(const float4*)&h[k0 + 4];
            float2 c2 = *(const float2*)&h[k0 + 8];
            hv[0] = a4.x; hv[1] = a4.y; hv[2] = a4.z; hv[3] = a4.w;
            hv[4] = b4.x; hv[5] = b4.y; hv[6] = b4.z; hv[7] = b4.w;
            hv[8] = c2.x; hv[9] = c2.y;
        }

        // 9 rows x 10 k partial dots (90 fmac, 9 independent chains)
        float a0 = 0.f, a1 = 0.f, a2 = 0.f, a3 = 0.f, a4 = 0.f,
              a5 = 0.f, a6 = 0.f, a7 = 0.f, a8 = 0.f;
        #pragma unroll
        for (int kk = 0; kk < 10; ++kk) {
            float hk = hv[kk];
            a0 = fmaf(w[0][kk], hk, a0);
            a1 = fmaf(w[1][kk], hk, a1);
            a2 = fmaf(w[2][kk], hk, a2);
            a3 = fmaf(w[3][kk], hk, a3);
            a4 = fmaf(w[4][kk], hk, a4);
            a5 = fmaf(w[5][kk], hk, a5);
            a6 = fmaf(w[6][kk], hk, a6);
            a7 = fmaf(w[7][kk], hk, a7);
            a8 = fmaf(w[8][kk], hk, a8);
        }

        // 16-lane all-reduce per accumulator (VALU pipe, no LDS)
        a0 = reduce16(a0); a1 = reduce16(a1); a2 = reduce16(a2);
        a3 = reduce16(a3); a4 = reduce16(a4); a5 = reduce16(a5);
        a6 = reduce16(a6); a7 = reduce16(a7); a8 = reduce16(a8);

        // lane s writes row 9g+s (s<9); all 16 lanes hold all 9 sums
        float myacc = a0;
        if (s == 1) myacc = a1;
        if (s == 2) myacc = a2;
        if (s == 3) myacc = a3;
        if (s == 4) myacc = a4;
        if (s == 5) myacc = a5;
        if (s == 6) myacc = a6;
        if (s == 7) myacc = a7;
        if (s == 8) myacc = a8;
        if (s < 9) gh[9 * g + s] = myacc + bias;
        __syncthreads();

        if (tid < D_) {
            float r = 1.f / (1.f + __expf(-(gir + gh[tid])));
            float z = 1.f / (1.f + __expf(-(giz + gh[D_ + tid])));
            float narg = gin + r * gh[2 * D_ + tid];
            narg = fminf(fmaxf(narg, -15.f), 15.f);
            float e2 = __expf(-2.f * narg);
            float nn = (1.f - e2) / (1.f + e2);
            float hn = (1.f - z) * nn + z * h[tid];
            hseq[(size_t)n * D_ + tid] = hn;
            h[tid] = hn;
        }
        __syncthreads();
    }

    if (tid < D_) hlast[b * D_ + tid] = h[tid];
}

// ---------------------------------------------------------------------------
extern "C" void kernel_launch(void* const* d_in, const int* in_sizes, int n_in,
                              void* d_out, int out_size, void* d_ws, size_t ws_size,
                              hipStream_t stream)
{
    const int*   x         = (const int*)d_in[0];
    // d_in[1] = lengths (unused by the reference computation)
    const float* hidden    = (const float*)d_in[2];
    const float* encode_w  = (const float*)d_in[3];
    const float* wchange_w = (const float*)d_in[4];
    const float* w_ih      = (const float*)d_in[5];
    const float* w_hh      = (const float*)d_in[6];
    const float* b_ih      = (const float*)d_in[7];
    const float* b_hh      = (const float*)d_in[8];
    const float* fc_w      = (const float*)d_in[9];
    const float* fc_b      = (const float*)d_in[10];

    float* out = (float*)d_out;              // [N_][128] then [128][144]
    float* ws  = (float*)d_ws;
    float* seq  = ws;                        //   921600 floats
    float* gi   = ws + 921600;               //  2764800 floats
    float* hseq = ws + 921600 + 2764800;     //   921600 floats  (18.4 MB total)

    // K1: embedding (parallel gather v2)
    embed_kernel<<<N_, 256, 0, stream>>>(x, encode_w, wchange_w, seq);

    // K2: gi = seq @ w_ih^T + b_ih   (M=6400, N=432)
    gemm_bias_kernel<<<dim3(N_ / 64, (G_ + 63) / 64), 256, 0, stream>>>(
        seq, w_ih, b_ih, gi, N_, G_);

    // K3: GRU over T=50  (v7: 768 threads, 12 waves)
    gru_kernel<<<B_, 768, 0, stream>>>(gi, w_hh, b_hh, hidden, hseq,
                                       out + (size_t)N_ * E_);

    // K4: dynamic_user = hseq @ fc_w^T + fc_b   (M=6400, N=128)
    gemm_bias_kernel<<<dim3(N_ / 64, E_ / 64), 256, 0, stream>>>(
        hseq, fc_w, fc_b, out, N_, E_);
}